// Round 6
// baseline (329.351 us; speedup 1.0000x reference)
//
#include <hip/hip_runtime.h>

#define THREADS 256

typedef unsigned short u16;
typedef __attribute__((ext_vector_type(8))) short bf16x8;
typedef __attribute__((ext_vector_type(4))) float f32x4;

// ---- helpers ----------------------------------------------------------
__device__ __forceinline__ u16 f2bf(float f) {
  unsigned int u = __float_as_uint(f);
  u += 0x7fffu + ((u >> 16) & 1u);   // RNE
  return (u16)(u >> 16);
}
__device__ __forceinline__ float bf2f(u16 s) {
  return __uint_as_float(((unsigned int)s) << 16);
}
__device__ __forceinline__ bf16x8 ld8g(const u16* p) {
  return *reinterpret_cast<const bf16x8*>(p);
}
__device__ __forceinline__ bf16x8 ld8s(const u16* p) {
  return *reinterpret_cast<const bf16x8*>(p);
}
__device__ __forceinline__ void st4bf(u16* dst, float4 v) {
  unsigned int lo = (unsigned int)f2bf(v.x) | ((unsigned int)f2bf(v.y) << 16);
  unsigned int hi = (unsigned int)f2bf(v.z) | ((unsigned int)f2bf(v.w) << 16);
  uint2 u; u.x = lo; u.y = hi;
  *reinterpret_cast<uint2*>(dst) = u;
}
__device__ __forceinline__ uint4 pack8(float4 a, float4 b) {
  uint4 r;
  r.x = (unsigned int)f2bf(a.x) | ((unsigned int)f2bf(a.y) << 16);
  r.y = (unsigned int)f2bf(a.z) | ((unsigned int)f2bf(a.w) << 16);
  r.z = (unsigned int)f2bf(b.x) | ((unsigned int)f2bf(b.y) << 16);
  r.w = (unsigned int)f2bf(b.z) | ((unsigned int)f2bf(b.w) << 16);
  return r;
}
// async global->LDS, 16 B per lane
typedef __attribute__((address_space(1))) const unsigned int g_u32;
typedef __attribute__((address_space(3))) unsigned int l_u32;
__device__ __forceinline__ void async16(const u16* g, u16* l) {
  __builtin_amdgcn_global_load_lds((g_u32*)g, (l_u32*)l, 16, 0, 0);
}

// c-blocked e2/alpha layout:
//   addr_u16(hm,i,j) = ((hm*4+it)*4 + wt)*4096 + (qt*16 + l15)*64 + r*16 + nt
//   where it=i>>6, wt=(i>>4)&3, qt=(i>>2)&3, r=i&3, l15=j&15, nt=j>>4.

// ---- phase 0: cast x + W's to bf16 ------------------------------------
__global__ __launch_bounds__(THREADS) void cast_xw(
    const float* __restrict__ x, const float* __restrict__ wq,
    const float* __restrict__ wk, const float* __restrict__ wv,
    u16* __restrict__ xb, u16* __restrict__ wqb, u16* __restrict__ wkb,
    u16* __restrict__ wvb) {
  int t = blockIdx.x * THREADS + threadIdx.x;
  if (t < 2097152) {
    st4bf(xb + t * 4, reinterpret_cast<const float4*>(x)[t]);
  } else if (t < 2162688) {
    int q = t - 2097152;
    st4bf(wqb + q * 4, reinterpret_cast<const float4*>(wq)[q]);
  } else if (t < 2228224) {
    int q = t - 2162688;
    st4bf(wkb + q * 4, reinterpret_cast<const float4*>(wk)[q]);
  } else if (t < 2293760) {
    int q = t - 2228224;
    st4bf(wvb + q * 4, reinterpret_cast<const float4*>(wv)[q]);
  }
}

// ---- phase 1: Q/K/V projection as one 16384x1536x512 GEMM -------------
__global__ __launch_bounds__(THREADS) void proj_gemm(
    const u16* __restrict__ xb, const u16* __restrict__ wb,
    u16* __restrict__ qh, u16* __restrict__ kb, u16* __restrict__ vt) {
  const int bm = blockIdx.x / 12, bn = blockIdx.x % 12;
  const int tid = threadIdx.x;
  const int wave = tid >> 6, lane = tid & 63;
  const int quad = lane >> 4, l15 = lane & 15;
  __shared__ __align__(16) u16 smem[9216];
  u16* At = smem;
  u16* Bt = smem + 4096;

  const int rowL = lane >> 2;
  const int chunkL = (lane & 3) ^ ((lane >> 3) & 3);
  const u16* gA = xb + (size_t)(bm * 128 + wave * 32 + rowL) * 512 + chunkL * 8;
  const u16* gB = wb + (size_t)(bn * 128 + wave * 32 + rowL) * 512 + chunkL * 8;
  u16* lA = At + wave * 1024;
  u16* lB = Bt + wave * 1024;

  const int rw0 = (wave & 1) * 64, cw0 = (wave >> 1) * 64;
  const int swz = (quad ^ ((l15 >> 1) & 3)) * 8;

  f32x4 acc[4][4];
#pragma unroll
  for (int mt = 0; mt < 4; ++mt)
#pragma unroll
    for (int nt = 0; nt < 4; ++nt) acc[mt][nt] = (f32x4){0.f, 0.f, 0.f, 0.f};

  for (int s = 0; s < 16; ++s) {
    __syncthreads();
    async16(gA + s * 32, lA);
    async16(gA + s * 32 + 8192, lA + 512);
    async16(gB + s * 32, lB);
    async16(gB + s * 32 + 8192, lB + 512);
    __syncthreads();
    bf16x8 af[4], bf[4];
#pragma unroll
    for (int mt = 0; mt < 4; ++mt)
      af[mt] = ld8s(At + (rw0 + mt * 16 + l15) * 32 + swz);
#pragma unroll
    for (int nt = 0; nt < 4; ++nt)
      bf[nt] = ld8s(Bt + (cw0 + nt * 16 + l15) * 32 + swz);
#pragma unroll
    for (int mt = 0; mt < 4; ++mt)
#pragma unroll
      for (int nt = 0; nt < 4; ++nt)
        acc[mt][nt] = __builtin_amdgcn_mfma_f32_16x16x32_bf16(af[mt], bf[nt], acc[mt][nt], 0, 0, 0);
  }

  const int mat = bn >> 2;
  const int h0 = (bn & 3) * 2;
  const int m = bm >> 1;
  const int l0 = (bm & 1) * 128;

  if (mat < 2) {
    u16* dstb = (mat == 0) ? qh : kb;
    const int il = tid >> 1, cc = (tid & 1) * 32;
#pragma unroll
    for (int p = 0; p < 2; ++p) {
      __syncthreads();
      if ((wave >> 1) == p) {
#pragma unroll
        for (int mt = 0; mt < 4; ++mt)
#pragma unroll
          for (int nt = 0; nt < 4; ++nt)
#pragma unroll
            for (int r = 0; r < 4; ++r)
              smem[(rw0 + mt * 16 + quad * 4 + r) * 72 + nt * 16 + l15] =
                  f2bf(acc[mt][nt][r]);
      }
      __syncthreads();
      u16* dst = dstb + ((size_t)((h0 + p) * 64 + m) * 256 + l0 + il) * 64 + cc;
      uint4 v0 = *reinterpret_cast<uint4*>(&smem[il * 72 + cc]);
      uint4 v1 = *reinterpret_cast<uint4*>(&smem[il * 72 + cc + 8]);
      uint4 v2 = *reinterpret_cast<uint4*>(&smem[il * 72 + cc + 16]);
      uint4 v3 = *reinterpret_cast<uint4*>(&smem[il * 72 + cc + 24]);
      *reinterpret_cast<uint4*>(dst) = v0;
      *reinterpret_cast<uint4*>(dst + 8) = v1;
      *reinterpret_cast<uint4*>(dst + 16) = v2;
      *reinterpret_cast<uint4*>(dst + 24) = v3;
    }
  } else {
    const int tl = tid >> 2, cc = (tid & 3) * 32;
#pragma unroll
    for (int p = 0; p < 2; ++p) {
      __syncthreads();
      if ((wave >> 1) == p) {
#pragma unroll
        for (int mt = 0; mt < 4; ++mt)
#pragma unroll
          for (int nt = 0; nt < 4; ++nt)
#pragma unroll
            for (int r = 0; r < 4; ++r)
              smem[(nt * 16 + l15) * 136 + rw0 + mt * 16 + quad * 4 + r] =
                  f2bf(acc[mt][nt][r]);
      }
      __syncthreads();
      int hm = (h0 + p) * 64 + m;
      u16* dst = vt + (size_t)hm * 16384 + tl * 256 + l0 + cc;
      uint4 v0 = *reinterpret_cast<uint4*>(&smem[tl * 136 + cc]);
      uint4 v1 = *reinterpret_cast<uint4*>(&smem[tl * 136 + cc + 8]);
      uint4 v2 = *reinterpret_cast<uint4*>(&smem[tl * 136 + cc + 16]);
      uint4 v3 = *reinterpret_cast<uint4*>(&smem[tl * 136 + cc + 24]);
      *reinterpret_cast<uint4*>(dst) = v0;
      *reinterpret_cast<uint4*>(dst + 8) = v1;
      *reinterpret_cast<uint4*>(dst + 16) = v2;
      *reinterpret_cast<uint4*>(dst + 24) = v3;
    }
  }
}

// ---- phase 2: e2 -> c-blocked layout ----------------------------------
__global__ __launch_bounds__(THREADS) void e2_k(
    const u16* __restrict__ qh, const float* __restrict__ aK,
    u16* __restrict__ e2c) {
  const int i = blockIdx.x >> 3, hmt = blockIdx.x & 7;
  const int tid = threadIdx.x;
  const int wave = tid >> 6, lane = tid & 63;
  const int quad = lane >> 4, l15 = lane & 15;
  __shared__ u16 aKl[256 * 72];   // (j, d) bf16, padded
#pragma unroll
  for (int c = 0; c < 8; ++c) {
    int fidx = c * 2048 + tid * 8;
    int j = fidx >> 6, d = fidx & 63;
    float4 f0 = *reinterpret_cast<const float4*>(aK + (size_t)i * 16384 + fidx);
    float4 f1 = *reinterpret_cast<const float4*>(aK + (size_t)i * 16384 + fidx + 4);
    *reinterpret_cast<uint4*>(&aKl[j * 72 + d]) = pack8(f0, f1);
  }
  __syncthreads();
  f32x4 acc[16];
#pragma unroll
  for (int nt = 0; nt < 16; ++nt) acc[nt] = (f32x4){0.f, 0.f, 0.f, 0.f};
  bf16x8 a[2];
#pragma unroll
  for (int ks = 0; ks < 2; ++ks)
    a[ks] = ld8g(qh + ((size_t)(hmt * 64 + wave * 16 + l15) * 256 + i) * 64 + ks * 32 + quad * 8);
#pragma unroll
  for (int nt = 0; nt < 16; ++nt) {
#pragma unroll
    for (int ks = 0; ks < 2; ++ks) {
      bf16x8 b = ld8s(&aKl[(nt * 16 + l15) * 72 + ks * 32 + quad * 8]);
      acc[nt] = __builtin_amdgcn_mfma_f32_16x16x32_bf16(a[ks], b, acc[nt], 0, 0, 0);
    }
  }
  const int it = i >> 6, wt = (i >> 4) & 3, qt = (i >> 2) & 3, rt = i & 3;
  u16* ebase = e2c + (size_t)(qt * 16 + l15) * 64 + rt * 16;
#pragma unroll
  for (int re = 0; re < 4; ++re) {
    int hm = hmt * 64 + wave * 16 + quad * 4 + re;
    u16 buf[16];
#pragma unroll
    for (int nt = 0; nt < 16; ++nt) buf[nt] = f2bf(acc[nt][re]);
    u16* d = ebase + ((size_t)(hm * 4 + it) * 4 + wt) * 4096;
    reinterpret_cast<uint4*>(d)[0] = reinterpret_cast<uint4*>(buf)[0];
    reinterpret_cast<uint4*>(d)[1] = reinterpret_cast<uint4*>(buf)[1];
  }
}

// ---- phase 3: fused scores+softmax+z1 — zero barriers -----------------
__global__ __launch_bounds__(THREADS) void attn_k(
    const u16* __restrict__ qh, const u16* __restrict__ kb,
    const u16* __restrict__ vt, u16* __restrict__ e2c,
    u16* __restrict__ z1p) {
  const int bi = blockIdx.x;
  const int hm = bi & 511, it = bi >> 9;   // it-major
  const int tid = threadIdx.x;
  const int wave = tid >> 6, lane = tid & 63;
  const int quad = lane >> 4, l15 = lane & 15;
  __shared__ u16 As[4 * 4224];             // per-wave 16 x 264 (wave-private)
  u16* W = &As[wave * 4224];

  // e2 (c-blocked): 128 B contiguous per lane, coalesced
  u16* eb = e2c + (((size_t)hm * 4 + it) * 4 + wave) * 4096 + (size_t)lane * 64;
  uint4 e2v[8];
#pragma unroll
  for (int c = 0; c < 8; ++c) e2v[c] = reinterpret_cast<const uint4*>(eb)[c];
  const u16* e2a = reinterpret_cast<const u16*>(e2v);  // [r*16 + nt]

  // e1 = Q K^T
  f32x4 acc[16];
#pragma unroll
  for (int nt = 0; nt < 16; ++nt) acc[nt] = (f32x4){0.f, 0.f, 0.f, 0.f};
  bf16x8 a[2];
#pragma unroll
  for (int ks = 0; ks < 2; ++ks)
    a[ks] = ld8g(qh + ((size_t)hm * 256 + it * 64 + wave * 16 + l15) * 64 + ks * 32 + quad * 8);
#pragma unroll
  for (int nt = 0; nt < 16; ++nt) {
#pragma unroll
    for (int ks = 0; ks < 2; ++ks) {
      bf16x8 b = ld8g(kb + ((size_t)hm * 256 + nt * 16 + l15) * 64 + ks * 32 + quad * 8);
      acc[nt] = __builtin_amdgcn_mfma_f32_16x16x32_bf16(a[ks], b, acc[nt], 0, 0, 0);
    }
  }
  // add e2 (registers) + scale
#pragma unroll
  for (int nt = 0; nt < 16; ++nt)
#pragma unroll
    for (int r = 0; r < 4; ++r)
      acc[nt][r] = (acc[nt][r] + bf2f(e2a[r * 16 + nt])) * 0.125f;

  // prefetch ks=0 V-fragments: latency hides behind the softmax below
  bf16x8 b2p[4];
#pragma unroll
  for (int nt = 0; nt < 4; ++nt)
    b2p[nt] = ld8g(vt + (size_t)hm * 16384 + (nt * 16 + l15) * 256 + quad * 8);

  // softmax over j; alpha -> a16 (c-blocked) + W (z1 transpose)
  u16 a16[64];
#pragma unroll
  for (int r = 0; r < 4; ++r) {
    float mx = -3.0e38f;
#pragma unroll
    for (int nt = 0; nt < 16; ++nt) mx = fmaxf(mx, acc[nt][r]);
    for (int msk = 1; msk < 16; msk <<= 1) mx = fmaxf(mx, __shfl_xor(mx, msk));
    float s = 0.f;
#pragma unroll
    for (int nt = 0; nt < 16; ++nt) {
      float p = __expf(acc[nt][r] - mx);
      acc[nt][r] = p;
      s += p;
    }
    for (int msk = 1; msk < 16; msk <<= 1) s += __shfl_xor(s, msk);
    float inv = 1.0f / s;
    int lrow = quad * 4 + r;
#pragma unroll
    for (int nt = 0; nt < 16; ++nt) {
      u16 pb = f2bf(acc[nt][r] * inv);
      a16[r * 16 + nt] = pb;
      W[lrow * 264 + nt * 16 + l15] = pb;
    }
  }
  // alpha -> global (c-blocked, coalesced; overwrites e2 slice)
#pragma unroll
  for (int c = 0; c < 8; ++c)
    reinterpret_cast<uint4*>(eb)[c] = reinterpret_cast<const uint4*>(a16)[c];

  // z1 = alpha @ V (A from wave-private LDS, B from vt via L2)
  f32x4 acc2[4];
#pragma unroll
  for (int nt = 0; nt < 4; ++nt) acc2[nt] = (f32x4){0.f, 0.f, 0.f, 0.f};
#pragma unroll
  for (int ks = 0; ks < 8; ++ks) {
    bf16x8 a2 = ld8s(&W[l15 * 264 + ks * 32 + quad * 8]);
#pragma unroll
    for (int nt = 0; nt < 4; ++nt) {
      bf16x8 b2 = (ks == 0) ? b2p[nt]
          : ld8g(vt + (size_t)hm * 16384 + (nt * 16 + l15) * 256 + ks * 32 + quad * 8);
      acc2[nt] = __builtin_amdgcn_mfma_f32_16x16x32_bf16(a2, b2, acc2[nt], 0, 0, 0);
    }
  }
  // z1 tile -> wave-private LDS -> coalesced store
#pragma unroll
  for (int nt = 0; nt < 4; ++nt)
#pragma unroll
    for (int r = 0; r < 4; ++r)
      W[(quad * 4 + r) * 264 + nt * 16 + l15] = f2bf(acc2[nt][r]);
  {
    int row = lane >> 2, col = (lane & 3) * 16;
    uint4 v0 = *reinterpret_cast<uint4*>(&W[row * 264 + col]);
    uint4 v1 = *reinterpret_cast<uint4*>(&W[row * 264 + col + 8]);
    u16* dst = z1p + (size_t)hm * 16384 + (it * 64 + wave * 16 + row) * 64 + col;
    *reinterpret_cast<uint4*>(dst) = v0;
    *reinterpret_cast<uint4*>(dst + 8) = v1;
  }
}

// ---- phase 4 (fused tail): beta + z2 + out, one block per i -----------
// grid 256. beta (sum_m alpha) -> LDS, z2 = beta @ aV[i] via MFMA,
// out[i][:] = z2 + sum_m z1p. No global intermediates.
__global__ __launch_bounds__(THREADS) void tail_k(
    const u16* __restrict__ alphac, const float* __restrict__ aV,
    const u16* __restrict__ z1p, float* __restrict__ out) {
  const int i = blockIdx.x;
  const int it = i >> 6, wt = (i >> 4) & 3, qt = (i >> 2) & 3, r = i & 3;
  const int tid = threadIdx.x;
  const int wave = tid >> 6, lane = tid & 63;
  const int quad = lane >> 4, l15 = lane & 15;
  __shared__ u16 aVl[64 * 264];      // aV[i]^T (d, j) bf16
  __shared__ float betaL[8 * 264];   // beta rows, padded (2-way-free b128)
  __shared__ float z2L[512];
  // stage aV[i] transposed
#pragma unroll
  for (int c = 0; c < 8; ++c) {
    int fidx = c * 2048 + tid * 8;
    int j = fidx >> 6, d = fidx & 63;
    float4 f0 = *reinterpret_cast<const float4*>(aV + (size_t)i * 16384 + fidx);
    float4 f1 = *reinterpret_cast<const float4*>(aV + (size_t)i * 16384 + fidx + 4);
    float fv[8] = {f0.x, f0.y, f0.z, f0.w, f1.x, f1.y, f1.z, f1.w};
#pragma unroll
    for (int u = 0; u < 8; ++u) aVl[(d + u) * 264 + j] = f2bf(fv[u]);
  }
  // beta: thread (h = tid>>5, u = tid&31): l15b = u>>1, nh = u&1 -> 8 j's
  {
    const int h = tid >> 5, u = tid & 31, l15b = u >> 1, nh = u & 1;
    const u16* base = alphac + (((size_t)(h * 64) * 4 + it) * 4 + wt) * 4096 +
                      (size_t)(qt * 16 + l15b) * 64 + r * 16 + nh * 8;
    float s[8] = {0.f, 0.f, 0.f, 0.f, 0.f, 0.f, 0.f, 0.f};
    for (int m = 0; m < 64; ++m) {
      uint4 v = *reinterpret_cast<const uint4*>(base + (size_t)m * 65536);
      const u16* p = reinterpret_cast<const u16*>(&v);
#pragma unroll
      for (int k = 0; k < 8; ++k) s[k] += bf2f(p[k]);
    }
#pragma unroll
    for (int k = 0; k < 8; ++k)
      betaL[h * 264 + (nh * 8 + k) * 16 + l15b] = s[k];
  }
  __syncthreads();
  // z2: M=16 (8 valid h), N=64 (wave*16), K=256
  {
    f32x4 acc = (f32x4){0.f, 0.f, 0.f, 0.f};
#pragma unroll
    for (int ks = 0; ks < 8; ++ks) {
      u16 ab[8];
      if (l15 < 8) {
        const float* bp = &betaL[l15 * 264 + ks * 32 + quad * 8];
#pragma unroll
        for (int u2 = 0; u2 < 8; ++u2) ab[u2] = f2bf(bp[u2]);
      } else {
#pragma unroll
        for (int u2 = 0; u2 < 8; ++u2) ab[u2] = 0;
      }
      bf16x8 a = *reinterpret_cast<bf16x8*>(ab);
      bf16x8 b = ld8s(&aVl[(wave * 16 + l15) * 264 + ks * 32 + quad * 8]);
      acc = __builtin_amdgcn_mfma_f32_16x16x32_bf16(a, b, acc, 0, 0, 0);
    }
#pragma unroll
    for (int rr = 0; rr < 4; ++rr) {
      int h = quad * 4 + rr;
      if (h < 8) z2L[h * 64 + wave * 16 + l15] = acc[rr];
    }
  }
  __syncthreads();
  // out: thread t -> e = 2t, 2t+1; m-sum of z1p + z2
  {
    int e0 = tid * 2;
    int h = e0 >> 6, d0 = e0 & 63;
    float s0 = z2L[e0], s1 = z2L[e0 + 1];
    const u16* zb = z1p + (size_t)(h * 64) * 16384 + (size_t)i * 64 + d0;
#pragma unroll 8
    for (int m = 0; m < 64; ++m) {
      unsigned int v = *reinterpret_cast<const unsigned int*>(zb + (size_t)m * 16384);
      s0 += bf2f((u16)(v & 0xffff));
      s1 += bf2f((u16)(v >> 16));
    }
    float2 o = {s0, s1};
    *reinterpret_cast<float2*>(out + (size_t)i * 512 + e0) = o;
  }
}

// ---- launch -----------------------------------------------------------
extern "C" void kernel_launch(void* const* d_in, const int* in_sizes, int n_in,
                              void* d_out, int out_size, void* d_ws, size_t ws_size,
                              hipStream_t stream) {
  const float* x  = (const float*)d_in[0];
  const float* wq = (const float*)d_in[1];
  const float* wk = (const float*)d_in[2];
  const float* wv = (const float*)d_in[3];
  const float* aK = (const float*)d_in[4];
  const float* aV = (const float*)d_in[5];
  float* out = (float*)d_out;

  char* ws = (char*)d_ws;
  u16* xb    = (u16*)(ws + 0);          // 16 MB (x bf16; later aliased by z1p)
  u16* wqb   = (u16*)(ws + 16777216);   // Wq/Wk/Wv contiguous = B (1536x512)
  u16* wkb   = (u16*)(ws + 17301504);
  u16* wvb   = (u16*)(ws + 17825792);
  u16* qh    = (u16*)(ws + 35127296);   // 16 MB (hm, i, d)
  u16* kb    = (u16*)(ws + 51904512);   // 16 MB (hm, j, d)
  u16* vt    = (u16*)(ws + 68681728);   // 16 MB (hm, d, j)
  u16* e2c   = (u16*)(ws + 85458944);   // 64 MB: e2/alpha, c-blocked layout
  u16* z1p   = xb;                      // 16 MB (hm, i, d), aliases xb

  cast_xw<<<8960, THREADS, 0, stream>>>(x, wq, wk, wv, xb, wqb, wkb, wvb);
  proj_gemm<<<1536, THREADS, 0, stream>>>(xb, wqb, qh, kb, vt);
  e2_k<<<2048, THREADS, 0, stream>>>(qh, aK, e2c);
  attn_k<<<2048, THREADS, 0, stream>>>(qh, kb, vt, e2c, z1p);
  tail_k<<<256, THREADS, 0, stream>>>(e2c, aV, z1p, out);
}

// Round 7
// 308.470 us; speedup vs baseline: 1.0677x; 1.0677x over previous
//
#include <hip/hip_runtime.h>

#define THREADS 256

typedef unsigned short u16;
typedef __attribute__((ext_vector_type(8))) short bf16x8;
typedef __attribute__((ext_vector_type(4))) float f32x4;

// ---- helpers ----------------------------------------------------------
__device__ __forceinline__ u16 f2bf(float f) {
  unsigned int u = __float_as_uint(f);
  u += 0x7fffu + ((u >> 16) & 1u);   // RNE
  return (u16)(u >> 16);
}
__device__ __forceinline__ float bf2f(u16 s) {
  return __uint_as_float(((unsigned int)s) << 16);
}
__device__ __forceinline__ bf16x8 ld8g(const u16* p) {
  return *reinterpret_cast<const bf16x8*>(p);
}
__device__ __forceinline__ bf16x8 ld8s(const u16* p) {
  return *reinterpret_cast<const bf16x8*>(p);
}
__device__ __forceinline__ void st4bf(u16* dst, float4 v) {
  unsigned int lo = (unsigned int)f2bf(v.x) | ((unsigned int)f2bf(v.y) << 16);
  unsigned int hi = (unsigned int)f2bf(v.z) | ((unsigned int)f2bf(v.w) << 16);
  uint2 u; u.x = lo; u.y = hi;
  *reinterpret_cast<uint2*>(dst) = u;
}
__device__ __forceinline__ uint4 pack8(float4 a, float4 b) {
  uint4 r;
  r.x = (unsigned int)f2bf(a.x) | ((unsigned int)f2bf(a.y) << 16);
  r.y = (unsigned int)f2bf(a.z) | ((unsigned int)f2bf(a.w) << 16);
  r.z = (unsigned int)f2bf(b.x) | ((unsigned int)f2bf(b.y) << 16);
  r.w = (unsigned int)f2bf(b.z) | ((unsigned int)f2bf(b.w) << 16);
  return r;
}
// async global->LDS, 16 B per lane
typedef __attribute__((address_space(1))) const unsigned int g_u32;
typedef __attribute__((address_space(3))) unsigned int l_u32;
__device__ __forceinline__ void async16(const u16* g, u16* l) {
  __builtin_amdgcn_global_load_lds((g_u32*)g, (l_u32*)l, 16, 0, 0);
}

// c-blocked e2/alpha layout:
//   addr_u16(hm,i,j) = ((hm*4+it)*4 + wt)*4096 + (qt*16 + l15)*64 + r*16 + nt
//   where it=i>>6, wt=(i>>4)&3, qt=(i>>2)&3, r=i&3, l15=j&15, nt=j>>4.

// ---- phase 0: cast x + W's to bf16 ------------------------------------
__global__ __launch_bounds__(THREADS) void cast_xw(
    const float* __restrict__ x, const float* __restrict__ wq,
    const float* __restrict__ wk, const float* __restrict__ wv,
    u16* __restrict__ xb, u16* __restrict__ wqb, u16* __restrict__ wkb,
    u16* __restrict__ wvb) {
  int t = blockIdx.x * THREADS + threadIdx.x;
  if (t < 2097152) {
    st4bf(xb + t * 4, reinterpret_cast<const float4*>(x)[t]);
  } else if (t < 2162688) {
    int q = t - 2097152;
    st4bf(wqb + q * 4, reinterpret_cast<const float4*>(wq)[q]);
  } else if (t < 2228224) {
    int q = t - 2162688;
    st4bf(wkb + q * 4, reinterpret_cast<const float4*>(wk)[q]);
  } else if (t < 2293760) {
    int q = t - 2228224;
    st4bf(wvb + q * 4, reinterpret_cast<const float4*>(wv)[q]);
  }
}

// ---- phase 1: Q/K/V projection as one 16384x1536x512 GEMM -------------
__global__ __launch_bounds__(THREADS) void proj_gemm(
    const u16* __restrict__ xb, const u16* __restrict__ wb,
    u16* __restrict__ qh, u16* __restrict__ kb, u16* __restrict__ vt) {
  const int bm = blockIdx.x / 12, bn = blockIdx.x % 12;
  const int tid = threadIdx.x;
  const int wave = tid >> 6, lane = tid & 63;
  const int quad = lane >> 4, l15 = lane & 15;
  __shared__ __align__(16) u16 smem[9216];
  u16* At = smem;
  u16* Bt = smem + 4096;

  const int rowL = lane >> 2;
  const int chunkL = (lane & 3) ^ ((lane >> 3) & 3);
  const u16* gA = xb + (size_t)(bm * 128 + wave * 32 + rowL) * 512 + chunkL * 8;
  const u16* gB = wb + (size_t)(bn * 128 + wave * 32 + rowL) * 512 + chunkL * 8;
  u16* lA = At + wave * 1024;
  u16* lB = Bt + wave * 1024;

  const int rw0 = (wave & 1) * 64, cw0 = (wave >> 1) * 64;
  const int swz = (quad ^ ((l15 >> 1) & 3)) * 8;

  f32x4 acc[4][4];
#pragma unroll
  for (int mt = 0; mt < 4; ++mt)
#pragma unroll
    for (int nt = 0; nt < 4; ++nt) acc[mt][nt] = (f32x4){0.f, 0.f, 0.f, 0.f};

  for (int s = 0; s < 16; ++s) {
    __syncthreads();
    async16(gA + s * 32, lA);
    async16(gA + s * 32 + 8192, lA + 512);
    async16(gB + s * 32, lB);
    async16(gB + s * 32 + 8192, lB + 512);
    __syncthreads();
    bf16x8 af[4], bf[4];
#pragma unroll
    for (int mt = 0; mt < 4; ++mt)
      af[mt] = ld8s(At + (rw0 + mt * 16 + l15) * 32 + swz);
#pragma unroll
    for (int nt = 0; nt < 4; ++nt)
      bf[nt] = ld8s(Bt + (cw0 + nt * 16 + l15) * 32 + swz);
#pragma unroll
    for (int mt = 0; mt < 4; ++mt)
#pragma unroll
      for (int nt = 0; nt < 4; ++nt)
        acc[mt][nt] = __builtin_amdgcn_mfma_f32_16x16x32_bf16(af[mt], bf[nt], acc[mt][nt], 0, 0, 0);
  }

  const int mat = bn >> 2;
  const int h0 = (bn & 3) * 2;
  const int m = bm >> 1;
  const int l0 = (bm & 1) * 128;

  if (mat < 2) {
    u16* dstb = (mat == 0) ? qh : kb;
    const int il = tid >> 1, cc = (tid & 1) * 32;
#pragma unroll
    for (int p = 0; p < 2; ++p) {
      __syncthreads();
      if ((wave >> 1) == p) {
#pragma unroll
        for (int mt = 0; mt < 4; ++mt)
#pragma unroll
          for (int nt = 0; nt < 4; ++nt)
#pragma unroll
            for (int r = 0; r < 4; ++r)
              smem[(rw0 + mt * 16 + quad * 4 + r) * 72 + nt * 16 + l15] =
                  f2bf(acc[mt][nt][r]);
      }
      __syncthreads();
      u16* dst = dstb + ((size_t)((h0 + p) * 64 + m) * 256 + l0 + il) * 64 + cc;
      uint4 v0 = *reinterpret_cast<uint4*>(&smem[il * 72 + cc]);
      uint4 v1 = *reinterpret_cast<uint4*>(&smem[il * 72 + cc + 8]);
      uint4 v2 = *reinterpret_cast<uint4*>(&smem[il * 72 + cc + 16]);
      uint4 v3 = *reinterpret_cast<uint4*>(&smem[il * 72 + cc + 24]);
      *reinterpret_cast<uint4*>(dst) = v0;
      *reinterpret_cast<uint4*>(dst + 8) = v1;
      *reinterpret_cast<uint4*>(dst + 16) = v2;
      *reinterpret_cast<uint4*>(dst + 24) = v3;
    }
  } else {
    const int tl = tid >> 2, cc = (tid & 3) * 32;
#pragma unroll
    for (int p = 0; p < 2; ++p) {
      __syncthreads();
      if ((wave >> 1) == p) {
#pragma unroll
        for (int mt = 0; mt < 4; ++mt)
#pragma unroll
          for (int nt = 0; nt < 4; ++nt)
#pragma unroll
            for (int r = 0; r < 4; ++r)
              smem[(nt * 16 + l15) * 136 + rw0 + mt * 16 + quad * 4 + r] =
                  f2bf(acc[mt][nt][r]);
      }
      __syncthreads();
      int hm = (h0 + p) * 64 + m;
      u16* dst = vt + (size_t)hm * 16384 + tl * 256 + l0 + cc;
      uint4 v0 = *reinterpret_cast<uint4*>(&smem[tl * 136 + cc]);
      uint4 v1 = *reinterpret_cast<uint4*>(&smem[tl * 136 + cc + 8]);
      uint4 v2 = *reinterpret_cast<uint4*>(&smem[tl * 136 + cc + 16]);
      uint4 v3 = *reinterpret_cast<uint4*>(&smem[tl * 136 + cc + 24]);
      *reinterpret_cast<uint4*>(dst) = v0;
      *reinterpret_cast<uint4*>(dst + 8) = v1;
      *reinterpret_cast<uint4*>(dst + 16) = v2;
      *reinterpret_cast<uint4*>(dst + 24) = v3;
    }
  }
}

// ---- phase 2: e2 -> c-blocked layout ----------------------------------
__global__ __launch_bounds__(THREADS) void e2_k(
    const u16* __restrict__ qh, const float* __restrict__ aK,
    u16* __restrict__ e2c) {
  const int i = blockIdx.x >> 3, hmt = blockIdx.x & 7;
  const int tid = threadIdx.x;
  const int wave = tid >> 6, lane = tid & 63;
  const int quad = lane >> 4, l15 = lane & 15;
  __shared__ u16 aKl[256 * 72];   // (j, d) bf16, padded
#pragma unroll
  for (int c = 0; c < 8; ++c) {
    int fidx = c * 2048 + tid * 8;
    int j = fidx >> 6, d = fidx & 63;
    float4 f0 = *reinterpret_cast<const float4*>(aK + (size_t)i * 16384 + fidx);
    float4 f1 = *reinterpret_cast<const float4*>(aK + (size_t)i * 16384 + fidx + 4);
    *reinterpret_cast<uint4*>(&aKl[j * 72 + d]) = pack8(f0, f1);
  }
  __syncthreads();
  f32x4 acc[16];
#pragma unroll
  for (int nt = 0; nt < 16; ++nt) acc[nt] = (f32x4){0.f, 0.f, 0.f, 0.f};
  bf16x8 a[2];
#pragma unroll
  for (int ks = 0; ks < 2; ++ks)
    a[ks] = ld8g(qh + ((size_t)(hmt * 64 + wave * 16 + l15) * 256 + i) * 64 + ks * 32 + quad * 8);
#pragma unroll
  for (int nt = 0; nt < 16; ++nt) {
#pragma unroll
    for (int ks = 0; ks < 2; ++ks) {
      bf16x8 b = ld8s(&aKl[(nt * 16 + l15) * 72 + ks * 32 + quad * 8]);
      acc[nt] = __builtin_amdgcn_mfma_f32_16x16x32_bf16(a[ks], b, acc[nt], 0, 0, 0);
    }
  }
  const int it = i >> 6, wt = (i >> 4) & 3, qt = (i >> 2) & 3, rt = i & 3;
  u16* ebase = e2c + (size_t)(qt * 16 + l15) * 64 + rt * 16;
#pragma unroll
  for (int re = 0; re < 4; ++re) {
    int hm = hmt * 64 + wave * 16 + quad * 4 + re;
    u16 buf[16];
#pragma unroll
    for (int nt = 0; nt < 16; ++nt) buf[nt] = f2bf(acc[nt][re]);
    u16* d = ebase + ((size_t)(hm * 4 + it) * 4 + wt) * 4096;
    reinterpret_cast<uint4*>(d)[0] = reinterpret_cast<uint4*>(buf)[0];
    reinterpret_cast<uint4*>(d)[1] = reinterpret_cast<uint4*>(buf)[1];
  }
}

// ---- phase 3: fused scores+softmax+z1 — zero barriers -----------------
__global__ __launch_bounds__(THREADS) void attn_k(
    const u16* __restrict__ qh, const u16* __restrict__ kb,
    const u16* __restrict__ vt, u16* __restrict__ e2c,
    u16* __restrict__ z1p) {
  const int bi = blockIdx.x;
  const int hm = bi & 511, it = bi >> 9;   // it-major
  const int tid = threadIdx.x;
  const int wave = tid >> 6, lane = tid & 63;
  const int quad = lane >> 4, l15 = lane & 15;
  __shared__ u16 As[4 * 4224];             // per-wave 16 x 264 (wave-private)
  u16* W = &As[wave * 4224];

  // e2 (c-blocked): 128 B contiguous per lane, coalesced
  u16* eb = e2c + (((size_t)hm * 4 + it) * 4 + wave) * 4096 + (size_t)lane * 64;
  uint4 e2v[8];
#pragma unroll
  for (int c = 0; c < 8; ++c) e2v[c] = reinterpret_cast<const uint4*>(eb)[c];
  const u16* e2a = reinterpret_cast<const u16*>(e2v);  // [r*16 + nt]

  // e1 = Q K^T
  f32x4 acc[16];
#pragma unroll
  for (int nt = 0; nt < 16; ++nt) acc[nt] = (f32x4){0.f, 0.f, 0.f, 0.f};
  bf16x8 a[2];
#pragma unroll
  for (int ks = 0; ks < 2; ++ks)
    a[ks] = ld8g(qh + ((size_t)hm * 256 + it * 64 + wave * 16 + l15) * 64 + ks * 32 + quad * 8);
#pragma unroll
  for (int nt = 0; nt < 16; ++nt) {
#pragma unroll
    for (int ks = 0; ks < 2; ++ks) {
      bf16x8 b = ld8g(kb + ((size_t)hm * 256 + nt * 16 + l15) * 64 + ks * 32 + quad * 8);
      acc[nt] = __builtin_amdgcn_mfma_f32_16x16x32_bf16(a[ks], b, acc[nt], 0, 0, 0);
    }
  }
  // add e2 (registers) + scale
#pragma unroll
  for (int nt = 0; nt < 16; ++nt)
#pragma unroll
    for (int r = 0; r < 4; ++r)
      acc[nt][r] = (acc[nt][r] + bf2f(e2a[r * 16 + nt])) * 0.125f;

  // prefetch ks=0 V-fragments: latency hides behind the softmax below
  bf16x8 b2p[4];
#pragma unroll
  for (int nt = 0; nt < 4; ++nt)
    b2p[nt] = ld8g(vt + (size_t)hm * 16384 + (nt * 16 + l15) * 256 + quad * 8);

  // softmax over j; alpha -> a16 (c-blocked) + W (z1 transpose)
  u16 a16[64];
#pragma unroll
  for (int r = 0; r < 4; ++r) {
    float mx = -3.0e38f;
#pragma unroll
    for (int nt = 0; nt < 16; ++nt) mx = fmaxf(mx, acc[nt][r]);
    for (int msk = 1; msk < 16; msk <<= 1) mx = fmaxf(mx, __shfl_xor(mx, msk));
    float s = 0.f;
#pragma unroll
    for (int nt = 0; nt < 16; ++nt) {
      float p = __expf(acc[nt][r] - mx);
      acc[nt][r] = p;
      s += p;
    }
    for (int msk = 1; msk < 16; msk <<= 1) s += __shfl_xor(s, msk);
    float inv = 1.0f / s;
    int lrow = quad * 4 + r;
#pragma unroll
    for (int nt = 0; nt < 16; ++nt) {
      u16 pb = f2bf(acc[nt][r] * inv);
      a16[r * 16 + nt] = pb;
      W[lrow * 264 + nt * 16 + l15] = pb;
    }
  }
  // alpha -> global (c-blocked, coalesced; overwrites e2 slice)
#pragma unroll
  for (int c = 0; c < 8; ++c)
    reinterpret_cast<uint4*>(eb)[c] = reinterpret_cast<const uint4*>(a16)[c];

  // z1 = alpha @ V (A from wave-private LDS, B from vt via L2)
  f32x4 acc2[4];
#pragma unroll
  for (int nt = 0; nt < 4; ++nt) acc2[nt] = (f32x4){0.f, 0.f, 0.f, 0.f};
#pragma unroll
  for (int ks = 0; ks < 8; ++ks) {
    bf16x8 a2 = ld8s(&W[l15 * 264 + ks * 32 + quad * 8]);
#pragma unroll
    for (int nt = 0; nt < 4; ++nt) {
      bf16x8 b2 = (ks == 0) ? b2p[nt]
          : ld8g(vt + (size_t)hm * 16384 + (nt * 16 + l15) * 256 + ks * 32 + quad * 8);
      acc2[nt] = __builtin_amdgcn_mfma_f32_16x16x32_bf16(a2, b2, acc2[nt], 0, 0, 0);
    }
  }
  // z1 tile -> wave-private LDS -> coalesced store
#pragma unroll
  for (int nt = 0; nt < 4; ++nt)
#pragma unroll
    for (int r = 0; r < 4; ++r)
      W[(quad * 4 + r) * 264 + nt * 16 + l15] = f2bf(acc2[nt][r]);
  {
    int row = lane >> 2, col = (lane & 3) * 16;
    uint4 v0 = *reinterpret_cast<uint4*>(&W[row * 264 + col]);
    uint4 v1 = *reinterpret_cast<uint4*>(&W[row * 264 + col + 8]);
    u16* dst = z1p + (size_t)hm * 16384 + (it * 64 + wave * 16 + row) * 64 + col;
    *reinterpret_cast<uint4*>(dst) = v0;
    *reinterpret_cast<uint4*>(dst + 8) = v1;
  }
}

// ---- phase 4: beta partials: betap[mc][i][h][j] = sum_{16 m} alpha ----
// grid 2048 = 512 (h,it,wt,qt) slices x 4 m-chunks. Coalesced uint4 reads.
__global__ __launch_bounds__(THREADS) void beta_k(
    const u16* __restrict__ alphac, float* __restrict__ betap) {
  const int b = blockIdx.x;
  const int slice = b >> 2, mc = b & 3;
  const int h = slice >> 6, it = (slice >> 4) & 3, wt = (slice >> 2) & 3, qt = slice & 3;
  const int tid = threadIdx.x;
  const int l15b = tid >> 4, sub = tid & 15, r = sub >> 2, ntq = sub & 3;
  const u16* base = alphac +
      (((size_t)(h * 64 + mc * 16) * 4 + it) * 4 + wt) * 4096 +
      (size_t)(qt * 16 + l15b) * 64 + r * 16 + ntq * 4;
  float s0 = 0.f, s1 = 0.f, s2 = 0.f, s3 = 0.f;
#pragma unroll 8
  for (int m = 0; m < 16; ++m) {
    uint2 v = *reinterpret_cast<const uint2*>(base + (size_t)m * 65536);
    const u16* p = reinterpret_cast<const u16*>(&v);
    s0 += bf2f(p[0]); s1 += bf2f(p[1]); s2 += bf2f(p[2]); s3 += bf2f(p[3]);
  }
  const int i = it * 64 + wt * 16 + qt * 4 + r;
  float* o = betap + (size_t)mc * 524288 + ((size_t)i * 8 + h) * 256 + l15b;
  o[(ntq * 4 + 0) * 16] = s0;
  o[(ntq * 4 + 1) * 16] = s1;
  o[(ntq * 4 + 2) * 16] = s2;
  o[(ntq * 4 + 3) * 16] = s3;
}

// ---- phase 5: z2b[i][h][d] = (sum_mc betap) @ aV[i] -------------------
__global__ __launch_bounds__(THREADS) void z2_k(
    const float* __restrict__ betap, const float* __restrict__ aV,
    float* __restrict__ z2b) {
  const int i = blockIdx.x;
  const int tid = threadIdx.x;
  const int wave = tid >> 6, lane = tid & 63;
  const int quad = lane >> 4, l15 = lane & 15;
  __shared__ u16 aVl[64 * 264];   // (d, j) bf16
#pragma unroll
  for (int c = 0; c < 8; ++c) {
    int fidx = c * 2048 + tid * 8;
    int j = fidx >> 6, d = fidx & 63;
    float4 f0 = *reinterpret_cast<const float4*>(aV + (size_t)i * 16384 + fidx);
    float4 f1 = *reinterpret_cast<const float4*>(aV + (size_t)i * 16384 + fidx + 4);
    float fv[8] = {f0.x, f0.y, f0.z, f0.w, f1.x, f1.y, f1.z, f1.w};
#pragma unroll
    for (int u = 0; u < 8; ++u) aVl[(d + u) * 264 + j] = f2bf(fv[u]);
  }
  __syncthreads();
  f32x4 acc = (f32x4){0.f, 0.f, 0.f, 0.f};
#pragma unroll
  for (int ks = 0; ks < 8; ++ks) {
    u16 ab[8];
    if (l15 < 8) {
      float s[8] = {0.f, 0.f, 0.f, 0.f, 0.f, 0.f, 0.f, 0.f};
#pragma unroll
      for (int mc = 0; mc < 4; ++mc) {
        const float* bp = betap + (size_t)mc * 524288 +
                          ((size_t)i * 8 + l15) * 256 + ks * 32 + quad * 8;
        float4 f0 = *reinterpret_cast<const float4*>(bp);
        float4 f1 = *reinterpret_cast<const float4*>(bp + 4);
        s[0] += f0.x; s[1] += f0.y; s[2] += f0.z; s[3] += f0.w;
        s[4] += f1.x; s[5] += f1.y; s[6] += f1.z; s[7] += f1.w;
      }
#pragma unroll
      for (int u2 = 0; u2 < 8; ++u2) ab[u2] = f2bf(s[u2]);
    } else {
#pragma unroll
      for (int u2 = 0; u2 < 8; ++u2) ab[u2] = 0;
    }
    bf16x8 a = *reinterpret_cast<bf16x8*>(ab);
    bf16x8 b = ld8s(&aVl[(wave * 16 + l15) * 264 + ks * 32 + quad * 8]);
    acc = __builtin_amdgcn_mfma_f32_16x16x32_bf16(a, b, acc, 0, 0, 0);
  }
#pragma unroll
  for (int r = 0; r < 4; ++r) {
    int h = quad * 4 + r;
    if (h < 8) z2b[(size_t)i * 512 + h * 64 + wave * 16 + l15] = acc[r];
  }
}

// ---- phase 6: out[i][e] = z2b[i][e] + sum_m z1p[(h,m)][i][d] ----------
__global__ __launch_bounds__(THREADS) void reduce_k(
    const u16* __restrict__ z1p, const float* __restrict__ z2b,
    float* __restrict__ out) {
  int o = blockIdx.x * THREADS + threadIdx.x;   // 131072 total
  int i = o >> 9, e = o & 511;
  int h = e >> 6, d = e & 63;
  float s = z2b[o];
  const u16* base = z1p + (size_t)(h * 64) * 16384 + (size_t)i * 64 + d;
#pragma unroll 8
  for (int m = 0; m < 64; ++m) s += bf2f(base[(size_t)m * 16384]);
  out[o] = s;
}

// ---- launch -----------------------------------------------------------
extern "C" void kernel_launch(void* const* d_in, const int* in_sizes, int n_in,
                              void* d_out, int out_size, void* d_ws, size_t ws_size,
                              hipStream_t stream) {
  const float* x  = (const float*)d_in[0];
  const float* wq = (const float*)d_in[1];
  const float* wk = (const float*)d_in[2];
  const float* wv = (const float*)d_in[3];
  const float* aK = (const float*)d_in[4];
  const float* aV = (const float*)d_in[5];
  float* out = (float*)d_out;

  char* ws = (char*)d_ws;
  u16* xb     = (u16*)(ws + 0);          // 16 MB (x bf16; later aliased by z1p)
  u16* wqb    = (u16*)(ws + 16777216);   // Wq/Wk/Wv contiguous = B (1536x512)
  u16* wkb    = (u16*)(ws + 17301504);
  u16* wvb    = (u16*)(ws + 17825792);
  float* betap= (float*)(ws + 18350080); // 8 MB (4 partials x 2 MB)
  float* z2b  = (float*)(ws + 26738688); // 0.5 MB
  u16* qh     = (u16*)(ws + 35127296);   // 16 MB (hm, i, d)
  u16* kb     = (u16*)(ws + 51904512);   // 16 MB (hm, j, d)
  u16* vt     = (u16*)(ws + 68681728);   // 16 MB (hm, d, j)
  u16* e2c    = (u16*)(ws + 85458944);   // 64 MB: e2/alpha, c-blocked layout
  u16* z1p    = xb;                      // 16 MB (hm, i, d), aliases xb

  cast_xw<<<8960, THREADS, 0, stream>>>(x, wq, wk, wv, xb, wqb, wkb, wvb);
  proj_gemm<<<1536, THREADS, 0, stream>>>(xb, wqb, qh, kb, vt);
  e2_k<<<2048, THREADS, 0, stream>>>(qh, aK, e2c);
  attn_k<<<2048, THREADS, 0, stream>>>(qh, kb, vt, e2c, z1p);
  beta_k<<<2048, THREADS, 0, stream>>>(e2c, betap);
  z2_k<<<256, THREADS, 0, stream>>>(betap, aV, z2b);
  reduce_k<<<512, THREADS, 0, stream>>>(z1p, z2b, out);
}